// Round 1
// baseline (982.002 us; speedup 1.0000x reference)
//
#include <hip/hip_runtime.h>
#include <cstdint>
#include <cstddef>

typedef __bf16 bf16;
typedef bf16 bf16x8 __attribute__((ext_vector_type(8)));
typedef float f32x4 __attribute__((ext_vector_type(4)));
typedef unsigned short u16;
typedef u16 u16x4 __attribute__((ext_vector_type(4)));
typedef u16 u16x8 __attribute__((ext_vector_type(8)));

__device__ __forceinline__ u16 f2bf(float f) {
    uint32_t u = __builtin_bit_cast(uint32_t, f);
    u += 0x7FFFu + ((u >> 16) & 1u);
    return (u16)(u >> 16);
}

#define AS1C(p) ((const __attribute__((address_space(1))) uint32_t*)(p))
#define AS3(p)  ((__attribute__((address_space(3))) uint32_t*)(p))

// ---------------------------------------------------------------------------
// Core: C[128x128] += A[128xK] * Bt[128xK]^T   (both operands K-contiguous)
// m97 structure: 256 thr (4 waves, 2x2 of 64x64), BK=32, global_load_lds w=16,
// mfma_f32_16x16x32_bf16. acc[mi][ni] C/D layout: col=lane&15, row=quad*4+r.
// ---------------------------------------------------------------------------
__device__ __forceinline__ void gemm_core(const bf16* __restrict__ Ablk,
                                          const bf16* __restrict__ Btblk,
                                          int lda, int ldb, int K,
                                          f32x4 acc[4][4])
{
    __shared__ bf16 lA[4096];   // [128 rows][32 k] row-major, no pad (gld_lds)
    __shared__ bf16 lB[4096];

    const int tid  = threadIdx.x;
    const int wave = tid >> 6;
    const int lane = tid & 63;
    const int lrow = lane >> 2;          // 0..15
    const int kcol = (lane & 3) << 3;    // 0,8,16,24

    // staging: each wave fills 32 rows of each tile via 2 issues of 1024B
    const bf16* ga0 = Ablk  + (size_t)(wave * 32 + lrow) * lda + kcol;
    const bf16* ga1 = ga0 + (size_t)16 * lda;
    const bf16* gb0 = Btblk + (size_t)(wave * 32 + lrow) * ldb + kcol;
    const bf16* gb1 = gb0 + (size_t)16 * ldb;
    bf16* la0 = &lA[wave * 1024];
    bf16* la1 = &lA[wave * 1024 + 512];
    bf16* lb0 = &lB[wave * 1024];
    bf16* lb1 = &lB[wave * 1024 + 512];

    const int wm    = (wave >> 1) * 64;
    const int wn    = (wave & 1) * 64;
    const int col16 = lane & 15;
    const int quad  = lane >> 4;
    const bf16* pa = &lA[(wm + col16) * 32 + quad * 8];
    const bf16* pb = &lB[(wn + col16) * 32 + quad * 8];

    for (int kb = 0; kb < K; kb += 32) {
        __builtin_amdgcn_global_load_lds(AS1C(ga0 + kb), AS3(la0), 16, 0, 0);
        __builtin_amdgcn_global_load_lds(AS1C(ga1 + kb), AS3(la1), 16, 0, 0);
        __builtin_amdgcn_global_load_lds(AS1C(gb0 + kb), AS3(lb0), 16, 0, 0);
        __builtin_amdgcn_global_load_lds(AS1C(gb1 + kb), AS3(lb1), 16, 0, 0);
        __syncthreads();

        bf16x8 av[4], bv[4];
        #pragma unroll
        for (int i = 0; i < 4; ++i) av[i] = *(const bf16x8*)(pa + i * 512);
        #pragma unroll
        for (int i = 0; i < 4; ++i) bv[i] = *(const bf16x8*)(pb + i * 512);

        #pragma unroll
        for (int mi = 0; mi < 4; ++mi)
            #pragma unroll
            for (int ni = 0; ni < 4; ++ni)
                acc[mi][ni] = __builtin_amdgcn_mfma_f32_16x16x32_bf16(
                    av[mi], bv[ni], acc[mi][ni], 0, 0, 0);
        __syncthreads();
    }
}

// ---------------------------------------------------------------------------
// fp32 -> bf16 cast, 8 elems/thread
// ---------------------------------------------------------------------------
__global__ __launch_bounds__(256) void cast_bf16(const float* __restrict__ src,
                                                 u16* __restrict__ dst, int n8)
{
    int i = blockIdx.x * 256 + threadIdx.x;
    if (i >= n8) return;
    const float4* s = (const float4*)src + (size_t)i * 2;
    float4 f0 = s[0], f1 = s[1];
    u16x8 o;
    o[0] = f2bf(f0.x); o[1] = f2bf(f0.y); o[2] = f2bf(f0.z); o[3] = f2bf(f0.w);
    o[4] = f2bf(f1.x); o[5] = f2bf(f1.y); o[6] = f2bf(f1.z); o[7] = f2bf(f1.w);
    *((u16x8*)dst + i) = o;
}

// ---------------------------------------------------------------------------
// GEMM1: fused QKV projection.  C = x(16384x2048) @ W^T + b, N regions k/q/v.
// q -> normal [16384][2048] bf16;  k,v -> transposed [bh][d][s] bf16.
// ---------------------------------------------------------------------------
__global__ __launch_bounds__(256) void gemm_qkv(
    const bf16* __restrict__ xb,
    const bf16* __restrict__ Wkb, const bf16* __restrict__ Wqb, const bf16* __restrict__ Wvb,
    const float* __restrict__ bk, const float* __restrict__ bq, const float* __restrict__ bv,
    u16* __restrict__ qout, u16* __restrict__ kT, u16* __restrict__ vT)
{
    const int bx = blockIdx.x;        // m block 0..127
    const int by = blockIdx.y;        // n block 0..47
    const int region = by >> 4;       // 0:k 1:q 2:v
    const int nloc = (by & 15) << 7;  // n within region, 0..1920

    const bf16* W     = (region == 0) ? Wkb : (region == 1) ? Wqb : Wvb;
    const float* bias = (region == 0) ? bk  : (region == 1) ? bq  : bv;

    f32x4 acc[4][4] = {};
    gemm_core(xb + (size_t)bx * 128 * 2048, W + (size_t)nloc * 2048,
              2048, 2048, 2048, acc);

    const int lane = threadIdx.x & 63, wave = threadIdx.x >> 6;
    const int wm = (wave >> 1) * 64, wn = (wave & 1) * 64;
    const int col16 = lane & 15, quad = lane >> 4;

    if (region == 1) {
        // q: normal store, feature-contiguous
        #pragma unroll
        for (int mi = 0; mi < 4; ++mi) {
            int row = bx * 128 + wm + mi * 16 + quad * 4;
            #pragma unroll
            for (int ni = 0; ni < 4; ++ni) {
                int col = nloc + wn + ni * 16 + col16;
                float b = bias[col];
                #pragma unroll
                for (int r = 0; r < 4; ++r)
                    qout[(size_t)(row + r) * 2048 + col] = f2bf(acc[mi][ni][r] + b);
            }
        }
    } else {
        // k/v: transposed store [bh][d][s]; 4 consecutive s (regs) pack to 8B
        u16* T = (region == 0) ? kT : vT;
        const int b_ = bx >> 5;           // 128 m-blocks / 32 per batch
        const int h_ = nloc >> 9;
        const int bh = b_ * 4 + h_;
        #pragma unroll
        for (int mi = 0; mi < 4; ++mi) {
            int s = ((bx & 31) * 128) + wm + mi * 16 + quad * 4;   // within 4096
            #pragma unroll
            for (int ni = 0; ni < 4; ++ni) {
                int fcol = nloc + wn + ni * 16 + col16;  // feature in region
                int d = fcol & 511;
                float b = bias[fcol];
                u16x4 p;
                #pragma unroll
                for (int r = 0; r < 4; ++r) p[r] = f2bf(acc[mi][ni][r] + b);
                *(u16x4*)&T[((size_t)(bh * 512 + d)) * 4096 + s] = p;
            }
        }
    }
}

// ---------------------------------------------------------------------------
// GEMM2: statesT[bh][e][d] = sum_s vT[bh][e][s] * kT[bh][d][s].  K=4096.
// ---------------------------------------------------------------------------
__global__ __launch_bounds__(256) void gemm_states(
    const u16* __restrict__ vT, const u16* __restrict__ kT, u16* __restrict__ ST)
{
    const int bh = blockIdx.z;
    const int m0 = blockIdx.x * 128;   // e
    const int n0 = blockIdx.y * 128;   // d

    f32x4 acc[4][4] = {};
    gemm_core((const bf16*)vT + (size_t)bh * 2097152 + (size_t)m0 * 4096,
              (const bf16*)kT + (size_t)bh * 2097152 + (size_t)n0 * 4096,
              4096, 4096, 4096, acc);

    const int lane = threadIdx.x & 63, wave = threadIdx.x >> 6;
    const int wm = (wave >> 1) * 64, wn = (wave & 1) * 64;
    const int col16 = lane & 15, quad = lane >> 4;
    #pragma unroll
    for (int mi = 0; mi < 4; ++mi) {
        int row = m0 + wm + mi * 16 + quad * 4;
        #pragma unroll
        for (int ni = 0; ni < 4; ++ni) {
            int col = n0 + wn + ni * 16 + col16;
            #pragma unroll
            for (int r = 0; r < 4; ++r)
                ST[(size_t)bh * 262144 + (size_t)(row + r) * 512 + col] =
                    f2bf(acc[mi][ni][r]);
        }
    }
}

// ---------------------------------------------------------------------------
// GEMM3: out[bh][s][e] = sum_d q[b][s][h*512+d] * statesT[bh][e][d].  K=512.
// ---------------------------------------------------------------------------
__global__ __launch_bounds__(256) void gemm_out(
    const u16* __restrict__ qb, const u16* __restrict__ ST, float* __restrict__ out)
{
    const int bh = blockIdx.z;
    const int b_ = bh >> 2, h_ = bh & 3;
    const int m0 = blockIdx.x * 128;   // s
    const int n0 = blockIdx.y * 128;   // e

    f32x4 acc[4][4] = {};
    gemm_core((const bf16*)qb + ((size_t)(b_ * 4096 + m0)) * 2048 + h_ * 512,
              (const bf16*)ST + (size_t)bh * 262144 + (size_t)n0 * 512,
              2048, 512, 512, acc);

    const int lane = threadIdx.x & 63, wave = threadIdx.x >> 6;
    const int wm = (wave >> 1) * 64, wn = (wave & 1) * 64;
    const int col16 = lane & 15, quad = lane >> 4;
    #pragma unroll
    for (int mi = 0; mi < 4; ++mi) {
        int row = m0 + wm + mi * 16 + quad * 4;
        #pragma unroll
        for (int ni = 0; ni < 4; ++ni) {
            int col = n0 + wn + ni * 16 + col16;
            #pragma unroll
            for (int r = 0; r < 4; ++r)
                out[(size_t)bh * 2097152 + (size_t)(row + r) * 512 + col] =
                    acc[mi][ni][r];
        }
    }
}

// ---------------------------------------------------------------------------
extern "C" void kernel_launch(void* const* d_in, const int* in_sizes, int n_in,
                              void* d_out, int out_size, void* d_ws, size_t ws_size,
                              hipStream_t stream)
{
    (void)in_sizes; (void)n_in; (void)out_size; (void)ws_size;
    const float* x  = (const float*)d_in[0];
    const float* Wk = (const float*)d_in[1];
    const float* bk = (const float*)d_in[2];
    const float* Wq = (const float*)d_in[3];
    const float* bq = (const float*)d_in[4];
    const float* Wv = (const float*)d_in[5];
    const float* bv = (const float*)d_in[6];
    float* out = (float*)d_out;

    // workspace layout (u16 elements), total 302 MB
    u16* ws  = (u16*)d_ws;
    u16* xb  = ws;                   // 16384*2048
    u16* Wkb = ws  + 33554432;       // 2048*2048
    u16* Wqb = Wkb + 4194304;
    u16* Wvb = Wqb + 4194304;
    u16* qb  = Wvb + 4194304;        // 16384*2048 (normal)
    u16* kT  = qb  + 33554432;       // [16][512][4096]
    u16* vT  = kT  + 33554432;       // [16][512][4096]
    u16* ST  = vT  + 33554432;       // [16][512][512]

    cast_bf16<<<16384, 256, 0, stream>>>(x,  xb,  4194304);
    cast_bf16<<<2048,  256, 0, stream>>>(Wk, Wkb, 524288);
    cast_bf16<<<2048,  256, 0, stream>>>(Wq, Wqb, 524288);
    cast_bf16<<<2048,  256, 0, stream>>>(Wv, Wvb, 524288);

    gemm_qkv<<<dim3(128, 48), 256, 0, stream>>>(
        (const bf16*)xb, (const bf16*)Wkb, (const bf16*)Wqb, (const bf16*)Wvb,
        bk, bq, bv, qb, kT, vT);

    gemm_states<<<dim3(4, 4, 16), 256, 0, stream>>>(vT, kT, ST);

    gemm_out<<<dim3(32, 4, 16), 256, 0, stream>>>(qb, ST, out);
}